// Round 2
// baseline (751.146 us; speedup 1.0000x reference)
//
#include <hip/hip_runtime.h>
#include <hip/hip_cooperative_groups.h>
#include <hip/hip_bf16.h>
#include <math.h>

typedef unsigned short u16;
typedef __attribute__((ext_vector_type(8))) short short8;
typedef __attribute__((ext_vector_type(4))) float f32x4;
typedef __attribute__((ext_vector_type(4))) unsigned short u16x4;

#define DEVINL static __device__ __forceinline__

DEVINL float b2f(u16 x) {
    union { unsigned u; float f; } v; v.u = ((unsigned)x) << 16; return v.f;
}
DEVINL u16 f2b(float f) {
    union { unsigned u; float f; } v; v.f = f;
    unsigned u = v.u;
    return (u16)((u + 0x7fffu + ((u >> 16) & 1u)) >> 16);
}
DEVINL float silu(float x) { return x * __fdividef(1.f, 1.f + __expf(-x)); }
DEVINL float ld_any(bool f32, const void* p, size_t i) {
    return f32 ? ((const float*)p)[i] : b2f(((const u16*)p)[i]);
}
template<bool F32> DEVINL float LDs(const void* p, size_t i) {
    if constexpr (F32) return ((const float*)p)[i];
    else               return b2f(((const u16*)p)[i]);
}

// Inline dtype detect: sample the 64 EVEN u16s of resnet. f32 input -> even
// u16s are mantissa halves; bf16 -> 0 triggers.
DEVINL bool detect_f32(const u16* __restrict__ raw) {
    int cnt = 0;
#pragma unroll
    for (int i = 0; i < 64; ++i) {
        float v = b2f(raw[i * 2]);
        if (!(fabsf(v) <= 1e3f)) cnt++;
    }
    return cnt > 0;
}

// --- converted-weights arena: element offsets inside w16 (bf16) ---
#define O_INW  0        /* 1024*256 */
#define O_XPW  262144   /* 48*512 */
#define O_OPW  286720   /* 256*512 */
#define O_SPW  417792   /* 256*512 */
#define O_CW   548864   /* 512*3 */
#define O_CB   550400   /* 512 */
#define O_DTW  550912   /* 512*16 */
#define O_ALOG 559104   /* 512*16 */
#define O_DTB  567296   /* 512 */
#define O_DW   567808   /* 512 */
#define O_SG   568320
#define O_SB   568576
#define O_SM   568832
#define O_SV   569088
#define O_RG   569344
#define O_RB   569600
#define O_RM   569856
#define O_RV   570112
#define O_LG   570368
#define O_LB   570624
#define N_CVT  570880
#define O_FLAG 570880   /* A_log == log(arange(1..16)) structure flag */

#define NCK 256   /* chunks per batch */
#define CLL 16    /* chunk length */

struct KP {
    const void *resnet, *scp, *spw, *sg, *sb, *sm, *sv, *rg, *rb, *rm, *rv,
               *lg, *lb, *inw, *cw, *cb, *xpw, *dtw, *dtb, *alog, *Dw, *opw;
    u16 *w16, *scpT, *resnetT, *xn, *sp16, *xz, *y, *hIn;
    float *xdf;
    unsigned *cAH;
    void *outp;
};

// ---------------------------------------------------------------------------
// P0: prep. 1884 work units over 512 blocks (<=4 iters). 512-thread blocks.
//   [0,1115)     weight cvt, 512 elems/unit (1115*512 == N_CVT exactly)
//   [1115,1371)  scp transpose tiles (256)
//   [1371,1883)  resnet transpose tiles (512)
//   1883         A_log structure check
// ---------------------------------------------------------------------------
DEVINL void tr_tile8(bool f32, const void* src, u16* dst, int R, int C,
                     int c0, int r0, int b, int tid, u16 (*t)[66])
{
    int lane = tid & 63, grp = tid >> 6;   // grp in [0,8)
#pragma unroll
    for (int j = 0; j < 8; ++j) {
        int rl = j * 8 + grp;
        t[rl][lane] = f2b(ld_any(f32, src, ((size_t)b * R + r0 + rl) * C + c0 + lane));
    }
    __syncthreads();
#pragma unroll
    for (int j = 0; j < 8; ++j) {
        int cl = j * 8 + grp;
        dst[((size_t)b * C + c0 + cl) * R + r0 + lane] = t[lane][cl];
    }
}

DEVINL void ph_prep(const KP& P, int blk, int tid, bool f32,
                    u16 (*t)[66], int* sh_ok)
{
    u16* __restrict__ w16 = P.w16;
    for (int id = blk; id < 1884; id += 512) {
        if (id < 1115) {
            int i = id * 512 + tid;
            const void* src; int off = i;
            if      (i < O_XPW)  { src = P.inw; }
            else if (i < O_OPW)  { src = P.xpw;  off = i - O_XPW; }
            else if (i < O_SPW)  { src = P.opw;  off = i - O_OPW; }
            else if (i < O_CW)   { src = P.spw;  off = i - O_SPW; }
            else if (i < O_CB)   { src = P.cw;   off = i - O_CW; }
            else if (i < O_DTW)  { src = P.cb;   off = i - O_CB; }
            else if (i < O_ALOG) { src = P.dtw;  off = i - O_DTW; }
            else if (i < O_DTB)  { src = P.alog; off = i - O_ALOG; }
            else if (i < O_DW)   { src = P.dtb;  off = i - O_DTB; }
            else if (i < O_SG)   { src = P.Dw;   off = i - O_DW; }
            else if (i < O_SB)   { src = P.sg;   off = i - O_SG; }
            else if (i < O_SM)   { src = P.sb;   off = i - O_SB; }
            else if (i < O_SV)   { src = P.sm;   off = i - O_SM; }
            else if (i < O_RG)   { src = P.sv;   off = i - O_SV; }
            else if (i < O_RB)   { src = P.rg;   off = i - O_RG; }
            else if (i < O_RM)   { src = P.rb;   off = i - O_RB; }
            else if (i < O_RV)   { src = P.rm;   off = i - O_RM; }
            else if (i < O_LG)   { src = P.rv;   off = i - O_RV; }
            else if (i < O_LB)   { src = P.lg;   off = i - O_LG; }
            else                 { src = P.lb;   off = i - O_LB; }
            w16[i] = f2b(ld_any(f32, src, off));
        } else if (id < 1371) {
            int tt = id - 1115;                  // scp: R=512, C=1024
            tr_tile8(f32, P.scp, P.scpT, 512, 1024,
                     (tt & 15) * 64, ((tt >> 4) & 7) * 64, tt >> 7, tid, t);
        } else if (id < 1883) {
            int tt = id - 1371;                  // resnet: R=256, C=4096
            tr_tile8(f32, P.resnet, P.resnetT, 256, 4096,
                     (tt & 63) * 64, ((tt >> 6) & 3) * 64, tt >> 8, tid, t);
        } else {
            if (tid == 0) *sh_ok = 1;
            __syncthreads();
            bool ok = true;
            for (int i = tid; i < 512 * 16; i += 512) {
                int s = i & 15;
                float av = -__expf(ld_any(f32, P.alog, i));
                if (fabsf(av + (float)(s + 1)) > 0.03f * (float)(s + 1)) ok = false;
            }
            if (!ok) atomicAnd(sh_ok, 0);
            __syncthreads();
            if (tid == 0) w16[O_FLAG] = (u16)(*sh_ok);
        }
        __syncthreads();   // protect LDS tile reuse across iterations
    }
}

// ---------------------------------------------------------------------------
// P1: scpmm. sp16[p][o] = BN(sum_c scpT[p][c] * spw[o][c]).
// 128 busy blocks (waves 0..3 of each), tile 64x64, wave 32x32.
// ---------------------------------------------------------------------------
DEVINL void ph_scpmm(const KP& P, int blk, int tid)
{
    if (blk >= 128) return;
    int lane = tid & 63, wid = tid >> 6;
    if (wid >= 4) return;
    const u16* __restrict__ w16 = P.w16;
    const int N = 256, K = 512;
    int ln = lane & 15, q = lane >> 4;
    int bx = blk & 31, by = blk >> 5;
    int m0 = bx * 64 + (wid & 1) * 32;
    int n0 = by * 64 + (wid >> 1) * 32;
    f32x4 acc00 = {0.f,0.f,0.f,0.f}, acc01 = acc00, acc10 = acc00, acc11 = acc00;
    const u16* Ap0 = P.scpT + (size_t)(m0 + ln) * K + q * 8;
    const u16* Ap1 = Ap0 + (size_t)16 * K;
    const u16* Wp = w16 + O_SPW;
#pragma unroll 4
    for (int k0 = 0; k0 < K; k0 += 32) {
        int kk = k0 + q * 8;
        short8 a0 = *reinterpret_cast<const short8*>(Ap0 + k0);
        short8 a1 = *reinterpret_cast<const short8*>(Ap1 + k0);
        short8 b0 = *reinterpret_cast<const short8*>(Wp + (size_t)(n0 + ln) * K + kk);
        short8 b1 = *reinterpret_cast<const short8*>(Wp + (size_t)(n0 + ln + 16) * K + kk);
        acc00 = __builtin_amdgcn_mfma_f32_16x16x32_bf16(a0, b0, acc00, 0, 0, 0);
        acc01 = __builtin_amdgcn_mfma_f32_16x16x32_bf16(a0, b1, acc01, 0, 0, 0);
        acc10 = __builtin_amdgcn_mfma_f32_16x16x32_bf16(a1, b0, acc10, 0, 0, 0);
        acc11 = __builtin_amdgcn_mfma_f32_16x16x32_bf16(a1, b1, acc11, 0, 0, 0);
    }
    int r0 = m0 + q * 4, c0 = n0 + ln;
    float inv0 = b2f(w16[O_SG + c0]) * rsqrtf(b2f(w16[O_SV + c0]) + 1e-5f);
    float sh0  = b2f(w16[O_SB + c0]) - b2f(w16[O_SM + c0]) * inv0;
    float inv1 = b2f(w16[O_SG + c0 + 16]) * rsqrtf(b2f(w16[O_SV + c0 + 16]) + 1e-5f);
    float sh1  = b2f(w16[O_SB + c0 + 16]) - b2f(w16[O_SM + c0 + 16]) * inv1;
#pragma unroll
    for (int r = 0; r < 4; ++r) {
        P.sp16[(size_t)(r0 + r) * N + c0]           = f2b(acc00[r] * inv0 + sh0);
        P.sp16[(size_t)(r0 + r) * N + c0 + 16]      = f2b(acc01[r] * inv1 + sh1);
        P.sp16[(size_t)(r0 + 16 + r) * N + c0]      = f2b(acc10[r] * inv0 + sh0);
        P.sp16[(size_t)(r0 + 16 + r) * N + c0 + 16] = f2b(acc11[r] * inv1 + sh1);
    }
}

// ---------------------------------------------------------------------------
// P2: ln. res-BN + bilinear + add -> LayerNorm -> xn.
// 512-thread block = two 256-thread subgroups (sub = batch), 8 rows each.
// ---------------------------------------------------------------------------
DEVINL void ph_ln(const KP& P, int blk, int tid, float (*red)[8])
{
    const u16* __restrict__ w16 = P.w16;
    int sub = tid >> 8, c = tid & 255, b = sub;
    float inv = b2f(w16[O_RG + c]) * rsqrtf(b2f(w16[O_RV + c]) + 1e-5f);
    float sh  = b2f(w16[O_RB + c]) - b2f(w16[O_RM + c]) * inv;
    float lgv = b2f(w16[O_LG + c]), lbv = b2f(w16[O_LB + c]);
    const u16* spc = P.sp16 + (size_t)b * 1024 * 256 + c;
    for (int j = 0; j < 8; ++j) {
        int l = blk * 8 + j;
        int h = l >> 6, w = l & 63;
        float rr = b2f(P.resnetT[((size_t)b * 4096 + l) * 256 + c]);
        float rn = rr * inv + sh;
        float xh = 0.5f * h - 0.25f; int jh = (int)floorf(xh); float fh = xh - jh;
        float xw = 0.5f * w - 0.25f; int jw = (int)floorf(xw); float fw = xw - jw;
        int h0 = jh < 0 ? 0 : jh, h1 = jh + 1 > 31 ? 31 : jh + 1;
        int w0 = jw < 0 ? 0 : jw, w1 = jw + 1 > 31 ? 31 : jw + 1;
        float v00 = b2f(spc[(size_t)(h0 * 32 + w0) * 256]), v01 = b2f(spc[(size_t)(h0 * 32 + w1) * 256]);
        float v10 = b2f(spc[(size_t)(h1 * 32 + w0) * 256]), v11 = b2f(spc[(size_t)(h1 * 32 + w1) * 256]);
        float sp = (1.f - fh) * ((1.f - fw) * v00 + fw * v01)
                 + fh * ((1.f - fw) * v10 + fw * v11);
        float fv = rn + sp;

        float s = fv, s2 = fv * fv;
#pragma unroll
        for (int off = 1; off < 64; off <<= 1) {
            s  += __shfl_xor(s, off);
            s2 += __shfl_xor(s2, off);
        }
        int wv = c >> 6;
        if ((c & 63) == 0) { red[sub][wv] = s; red[sub][4 + wv] = s2; }
        __syncthreads();
        float S  = red[sub][0] + red[sub][1] + red[sub][2] + red[sub][3];
        float S2 = red[sub][4] + red[sub][5] + red[sub][6] + red[sub][7];
        __syncthreads();
        float mu   = S * (1.f / 256.f);
        float var  = S2 * (1.f / 256.f) - mu * mu;
        float rstd = rsqrtf(var + 1e-5f);
        P.xn[((size_t)b * 4096 + l) * 256 + c] = f2b((fv - mu) * rstd * lgv + lbv);
    }
}

// ---------------------------------------------------------------------------
// P3: in_proj GEMM. M=8192, N=1024, K=256. Block 128m x 128n (8 waves 2x4),
// wave tile 64x32 (8 MFMA/k-iter, low VGPR). All 512 blocks busy.
// ---------------------------------------------------------------------------
DEVINL void ph_gemm_in(const KP& P, int blk, int tid)
{
    const int Nn = 1024, K = 256;
    int lane = tid & 63, wid = tid >> 6;
    int ln = lane & 15, q = lane >> 4;
    int bx = blk & 63, by = blk >> 6;
    int m0 = bx * 128 + (wid & 1) * 64;
    int n0 = by * 128 + (wid >> 1) * 32;
    f32x4 acc[4][2];
#pragma unroll
    for (int i = 0; i < 4; ++i)
#pragma unroll
        for (int j = 0; j < 2; ++j) acc[i][j] = {0.f,0.f,0.f,0.f};
    const u16* Ap = P.xn + (size_t)(m0 + ln) * K + q * 8;
    const u16* Bp = P.w16 + O_INW + (size_t)(n0 + ln) * K + q * 8;
#pragma unroll
    for (int k0 = 0; k0 < K; k0 += 32) {
        short8 a[4], bb[2];
#pragma unroll
        for (int i = 0; i < 4; ++i)
            a[i] = *reinterpret_cast<const short8*>(Ap + (size_t)(16 * i) * K + k0);
#pragma unroll
        for (int j = 0; j < 2; ++j)
            bb[j] = *reinterpret_cast<const short8*>(Bp + (size_t)(16 * j) * K + k0);
#pragma unroll
        for (int i = 0; i < 4; ++i)
#pragma unroll
            for (int j = 0; j < 2; ++j)
                acc[i][j] = __builtin_amdgcn_mfma_f32_16x16x32_bf16(a[i], bb[j], acc[i][j], 0, 0, 0);
    }
    int r0 = m0 + q * 4, c0 = n0 + ln;
#pragma unroll
    for (int i = 0; i < 4; ++i)
#pragma unroll
        for (int j = 0; j < 2; ++j)
#pragma unroll
            for (int r = 0; r < 4; ++r)
                P.xz[(size_t)(r0 + 16 * i + r) * Nn + c0 + 16 * j] = f2b(acc[i][j][r]);
}

// ---------------------------------------------------------------------------
// on-the-fly u fragment: u[row][kk0..kk0+8) = silu(causal conv3 of xm half)
// ---------------------------------------------------------------------------
DEVINL short8 u_frag(const u16* __restrict__ xz, const u16* __restrict__ w16,
                     int row, int kk0)
{
    int l = row & 4095;
    const u16* p = xz + (size_t)row * 1024 + kk0;
    short8 zz = {0,0,0,0,0,0,0,0};
    short8 x0 = *reinterpret_cast<const short8*>(p);
    short8 x1 = (l >= 1) ? *reinterpret_cast<const short8*>(p - 1024) : zz;
    short8 x2 = (l >= 2) ? *reinterpret_cast<const short8*>(p - 2048) : zz;
    short8 r;
#pragma unroll
    for (int j = 0; j < 8; ++j) {
        int d = kk0 + j;
        float acc = b2f(w16[O_CB + d])
                  + b2f((u16)x2[j]) * b2f(w16[O_CW + d * 3])
                  + b2f((u16)x1[j]) * b2f(w16[O_CW + d * 3 + 1])
                  + b2f((u16)x0[j]) * b2f(w16[O_CW + d * 3 + 2]);
        r[j] = (short)f2b(silu(acc));
    }
    return r;
}

// ---------------------------------------------------------------------------
// P4: x_proj GEMM, conv-on-the-fly A. 256 busy blocks, 32 rows each:
// two 16-row groups x 4-way K-split (K=128/wave) + LDS reduce.
// Fixes the old 2-waves/CU starvation (512 -> 2048 waves).
// ---------------------------------------------------------------------------
DEVINL void ph_xproj(const KP& P, int blk, int tid, float (*xred)[4][64][12])
{
    if (blk >= 256) return;
    int lane = tid & 63, wid = tid >> 6;
    int ln = lane & 15, q = lane >> 4;
    int grp = wid >> 2, wsub = wid & 3;
    int m0 = blk * 32 + grp * 16;
    const u16* Wp = P.w16 + O_XPW;
    f32x4 acc[3];
#pragma unroll
    for (int j = 0; j < 3; ++j) acc[j] = {0.f,0.f,0.f,0.f};
    int kb = wsub * 128;
    for (int k0 = kb; k0 < kb + 128; k0 += 32) {
        int kk0 = k0 + q * 8;
        short8 a0 = u_frag(P.xz, P.w16, m0 + ln, kk0);
#pragma unroll
        for (int j = 0; j < 3; ++j) {
            short8 bj = *reinterpret_cast<const short8*>(Wp + (size_t)(16 * j + ln) * 512 + kk0);
            acc[j] = __builtin_amdgcn_mfma_f32_16x16x32_bf16(a0, bj, acc[j], 0, 0, 0);
        }
    }
#pragma unroll
    for (int j = 0; j < 3; ++j)
#pragma unroll
        for (int r = 0; r < 4; ++r) xred[grp][wsub][lane][j * 4 + r] = acc[j][r];
    __syncthreads();
    if (wsub == 0) {
#pragma unroll
        for (int j = 0; j < 3; ++j)
#pragma unroll
            for (int r = 0; r < 4; ++r) {
                float v = xred[grp][0][lane][j * 4 + r] + xred[grp][1][lane][j * 4 + r]
                        + xred[grp][2][lane][j * 4 + r] + xred[grp][3][lane][j * 4 + r];
                P.xdf[(size_t)(m0 + q * 4 + r) * 48 + 16 * j + ln] = v;
            }
    }
}

// per-step shared scan prelude: conv -> silu -> dt-dot -> softplus
#define SCAN_PRELUDE()                                                        \
    const float* xr = xr0 + (size_t)il * 48;                                  \
    float x0 = b2f(xz[xbase + (size_t)il * 1024]);                            \
    float uv = silu(cbv + cw0 * x2 + cw1 * x1 + cw2 * x0);                    \
    float pa = 0.f, pb = 0.f, pc = 0.f, pq = 0.f;                             \
    _Pragma("unroll")                                                         \
    for (int j = 0; j < 4; ++j) {                                             \
        pa += xr[j]      * wdt[j];      pb += xr[4 + j]  * wdt[4 + j];        \
        pc += xr[8 + j]  * wdt[8 + j];  pq += xr[12 + j] * wdt[12 + j];       \
    }                                                                         \
    float accd = bias + ((pa + pb) + (pc + pq));                              \
    float dtv = accd > 15.f ? accd : __logf(1.f + __expf(accd));              \
    float du = dtv * uv;

// ---------------------------------------------------------------------------
// P5: scan1. 512 blocks = (b, ck); d = tid. Writes packed (ap|h_local).
// ---------------------------------------------------------------------------
DEVINL void ph_scan1(const KP& P, int blk, int tid)
{
    const u16* __restrict__ w16 = P.w16;
    const u16* __restrict__ xz = P.xz;
    int d = tid, ck = blk & 255, b = blk >> 8;
    float wdt[16];
#pragma unroll
    for (int j = 0; j < 16; ++j) wdt[j] = b2f(w16[O_DTW + d * 16 + j]);
    float bias = b2f(w16[O_DTB + d]);
    float cw0 = b2f(w16[O_CW + d * 3]), cw1 = b2f(w16[O_CW + d * 3 + 1]),
          cw2 = b2f(w16[O_CW + d * 3 + 2]), cbv = b2f(w16[O_CB + d]);
    int l0 = ck * CLL;
    size_t xbase = ((size_t)b * 4096 + l0) * 1024 + d;
    float x2 = (l0 >= 2) ? b2f(xz[xbase - 2048]) : 0.f;
    float x1 = (l0 >= 1) ? b2f(xz[xbase - 1024]) : 0.f;
    const float* xr0 = P.xdf + ((size_t)b * 4096 + l0) * 48;
    size_t obase = (((size_t)b * NCK + ck) * 16) * 512 + d;
    float h[16];
#pragma unroll
    for (int s = 0; s < 16; ++s) h[s] = 0.f;

    if (w16[O_FLAG]) {
        float sdt = 0.f;
#pragma unroll 2
        for (int il = 0; il < CLL; ++il) {
            SCAN_PRELUDE();
            sdt += dtv;
            float e1 = __expf(-dtv);
            float e2 = e1 * e1, e3 = e2 * e1, e4 = e2 * e2;
            float e8 = e4 * e4, e12 = e8 * e4;
            float inn[4] = {e1, e2, e3, e4};
            float bas[4] = {1.f, e4, e8, e12};
#pragma unroll
            for (int s = 0; s < 16; ++s)
                h[s] = (bas[s >> 2] * inn[s & 3]) * h[s] + du * xr[16 + s];
            x2 = x1; x1 = x0;
        }
        float E1 = __expf(-sdt);
        float E2 = E1 * E1, E3 = E2 * E1, E4 = E2 * E2;
        float E8 = E4 * E4, E12 = E8 * E4;
        float iN[4] = {E1, E2, E3, E4};
        float bA[4] = {1.f, E4, E8, E12};
#pragma unroll
        for (int s = 0; s < 16; ++s)
            P.cAH[obase + (size_t)s * 512] =
                (unsigned)f2b(bA[s >> 2] * iN[s & 3]) | ((unsigned)f2b(h[s]) << 16);
    } else {
        float a[16], ap[16];
#pragma unroll
        for (int s = 0; s < 16; ++s) {
            a[s] = -__expf(b2f(w16[O_ALOG + d * 16 + s]));
            ap[s] = 1.f;
        }
        for (int il = 0; il < CLL; ++il) {
            SCAN_PRELUDE();
#pragma unroll
            for (int s = 0; s < 16; ++s) {
                float dA = __expf(dtv * a[s]);
                h[s] = dA * h[s] + du * xr[16 + s];
                ap[s] *= dA;
            }
            x2 = x1; x1 = x0;
        }
#pragma unroll
        for (int s = 0; s < 16; ++s)
            P.cAH[obase + (size_t)s * 512] =
                (unsigned)f2b(ap[s]) | ((unsigned)f2b(h[s]) << 16);
    }
}

// ---------------------------------------------------------------------------
// P6: scan2 cross-chunk recurrence. 32 busy blocks: b = blk>>4, s = blk&15.
// ---------------------------------------------------------------------------
DEVINL void ph_scan2(const KP& P, int blk, int tid)
{
    if (blk >= 32) return;
    int b = blk >> 4, s = blk & 15, d = tid;
    float h = 0.f;
#pragma unroll 8
    for (int ck = 0; ck < NCK; ++ck) {
        size_t idx = (((size_t)b * NCK + ck) * 16 + s) * 512 + d;
        unsigned v = P.cAH[idx];
        float aP = b2f((u16)(v & 0xffffu));
        float hE = b2f((u16)(v >> 16));
        P.hIn[idx] = f2b(h);
        h = aP * h + hE;
    }
}

// ---------------------------------------------------------------------------
// P7: scan3 replay from h_in; y = (h.C + u*D) * silu(z).
// ---------------------------------------------------------------------------
DEVINL void ph_scan3(const KP& P, int blk, int tid)
{
    const u16* __restrict__ w16 = P.w16;
    const u16* __restrict__ xz = P.xz;
    int d = tid, ck = blk & 255, b = blk >> 8;
    float wdt[16];
#pragma unroll
    for (int j = 0; j < 16; ++j) wdt[j] = b2f(w16[O_DTW + d * 16 + j]);
    float bias = b2f(w16[O_DTB + d]);
    float Dv = b2f(w16[O_DW + d]);
    float cw0 = b2f(w16[O_CW + d * 3]), cw1 = b2f(w16[O_CW + d * 3 + 1]),
          cw2 = b2f(w16[O_CW + d * 3 + 2]), cbv = b2f(w16[O_CB + d]);
    int l0 = ck * CLL;
    size_t xbase = ((size_t)b * 4096 + l0) * 1024 + d;
    float x2 = (l0 >= 2) ? b2f(xz[xbase - 2048]) : 0.f;
    float x1 = (l0 >= 1) ? b2f(xz[xbase - 1024]) : 0.f;
    const float* xr0 = P.xdf + ((size_t)b * 4096 + l0) * 48;
    size_t obase = (((size_t)b * NCK + ck) * 16) * 512 + d;
    float h[16];
#pragma unroll
    for (int s = 0; s < 16; ++s) h[s] = b2f(P.hIn[obase + (size_t)s * 512]);

    if (w16[O_FLAG]) {
#pragma unroll 2
        for (int il = 0; il < CLL; ++il) {
            SCAN_PRELUDE();
            float e1 = __expf(-dtv);
            float e2 = e1 * e1, e3 = e2 * e1, e4 = e2 * e2;
            float e8 = e4 * e4, e12 = e8 * e4;
            float inn[4] = {e1, e2, e3, e4};
            float bas[4] = {1.f, e4, e8, e12};
            float yv = 0.f;
#pragma unroll
            for (int s = 0; s < 16; ++s) {
                h[s] = (bas[s >> 2] * inn[s & 3]) * h[s] + du * xr[16 + s];
                yv += h[s] * xr[32 + s];
            }
            size_t row = (size_t)b * 4096 + l0 + il;
            yv += uv * Dv;
            float zv = b2f(xz[row * 1024 + 512 + d]);
            yv *= silu(zv);
            P.y[row * 512 + d] = f2b(yv);
            x2 = x1; x1 = x0;
        }
    } else {
        float a[16];
#pragma unroll
        for (int s = 0; s < 16; ++s)
            a[s] = -__expf(b2f(w16[O_ALOG + d * 16 + s]));
        for (int il = 0; il < CLL; ++il) {
            SCAN_PRELUDE();
            float yv = 0.f;
#pragma unroll
            for (int s = 0; s < 16; ++s) {
                float dA = __expf(dtv * a[s]);
                h[s] = dA * h[s] + du * xr[16 + s];
                yv += h[s] * xr[32 + s];
            }
            size_t row = (size_t)b * 4096 + l0 + il;
            yv += uv * Dv;
            float zv = b2f(xz[row * 1024 + 512 + d]);
            yv *= silu(zv);
            P.y[row * 512 + d] = f2b(yv);
            x2 = x1; x1 = x0;
        }
    }
}

// ---------------------------------------------------------------------------
// P8: out_proj GEMM + fused-recompute epilogue. 256 busy blocks:
// block tile 64chan x 128seq (8 waves 2x4), wave 32x32.
// ---------------------------------------------------------------------------
template<bool F32> DEVINL void ph_out(const KP& P, int blk, int tid)
{
    if (blk >= 256) return;
    const u16* __restrict__ w16 = P.w16;
    const int K = 512;
    int lane = tid & 63, wid = tid >> 6;
    int ln = lane & 15, q = lane >> 4;
    int fx = blk & 3, fy = blk >> 2;
    int m0 = fx * 64 + (wid & 1) * 32;     // channel dim (256)
    int n0 = fy * 128 + (wid >> 1) * 32;   // sequence dim (8192)
    f32x4 acc[2][2];
#pragma unroll
    for (int i = 0; i < 2; ++i)
#pragma unroll
        for (int j = 0; j < 2; ++j) acc[i][j] = {0.f,0.f,0.f,0.f};
    const u16* Ap0 = w16 + O_OPW + (size_t)(m0 + ln) * K + q * 8;
    const u16* Ap1 = Ap0 + (size_t)16 * K;
    const u16* Bp0 = P.y + (size_t)(n0 + ln) * K + q * 8;
    const u16* Bp1 = Bp0 + (size_t)16 * K;
#pragma unroll 2
    for (int k0 = 0; k0 < K; k0 += 32) {
        short8 a0 = *reinterpret_cast<const short8*>(Ap0 + k0);
        short8 a1 = *reinterpret_cast<const short8*>(Ap1 + k0);
        short8 b0 = *reinterpret_cast<const short8*>(Bp0 + k0);
        short8 b1 = *reinterpret_cast<const short8*>(Bp1 + k0);
        acc[0][0] = __builtin_amdgcn_mfma_f32_16x16x32_bf16(a0, b0, acc[0][0], 0, 0, 0);
        acc[0][1] = __builtin_amdgcn_mfma_f32_16x16x32_bf16(a0, b1, acc[0][1], 0, 0, 0);
        acc[1][0] = __builtin_amdgcn_mfma_f32_16x16x32_bf16(a1, b0, acc[1][0], 0, 0, 0);
        acc[1][1] = __builtin_amdgcn_mfma_f32_16x16x32_bf16(a1, b1, acc[1][1], 0, 0, 0);
    }
    int r0 = m0 + q * 4;
    int nb = n0 + ln;
    float inv8[2][4], sh8[2][4];
#pragma unroll
    for (int im = 0; im < 2; ++im)
#pragma unroll
        for (int r = 0; r < 4; ++r) {
            int c = r0 + 16 * im + r;
            float inv = b2f(w16[O_RG + c]) * rsqrtf(b2f(w16[O_RV + c]) + 1e-5f);
            inv8[im][r] = inv;
            sh8[im][r]  = b2f(w16[O_RB + c]) - b2f(w16[O_RM + c]) * inv;
        }
#pragma unroll
    for (int jn = 0; jn < 2; ++jn) {
        int n = nb + 16 * jn;
        int b = n >> 12, l = n & 4095;
        int hh = l >> 6, w = l & 63;
        float xh = 0.5f * hh - 0.25f; int jh = (int)floorf(xh); float fh = xh - jh;
        float xw = 0.5f * w - 0.25f;  int jw = (int)floorf(xw); float fw = xw - jw;
        int h0 = jh < 0 ? 0 : jh, h1 = jh + 1 > 31 ? 31 : jh + 1;
        int w0 = jw < 0 ? 0 : jw, w1 = jw + 1 > 31 ? 31 : jw + 1;
        float w00 = (1.f - fh) * (1.f - fw), w01 = (1.f - fh) * fw;
        float w10 = fh * (1.f - fw),         w11 = fh * fw;
        const u16* spb = P.sp16 + (size_t)b * 1024 * 256;
#pragma unroll
        for (int im = 0; im < 2; ++im) {
            int cb = r0 + 16 * im;
            u16x4 s00 = *reinterpret_cast<const u16x4*>(spb + (size_t)(h0 * 32 + w0) * 256 + cb);
            u16x4 s01 = *reinterpret_cast<const u16x4*>(spb + (size_t)(h0 * 32 + w1) * 256 + cb);
            u16x4 s10 = *reinterpret_cast<const u16x4*>(spb + (size_t)(h1 * 32 + w0) * 256 + cb);
            u16x4 s11 = *reinterpret_cast<const u16x4*>(spb + (size_t)(h1 * 32 + w1) * 256 + cb);
#pragma unroll
            for (int r = 0; r < 4; ++r) {
                int c = cb + r;
                float rr = LDs<F32>(P.resnet, ((size_t)b * 256 + c) * 4096 + l);
                float sp = w00 * b2f(s00[r]) + w01 * b2f(s01[r])
                         + w10 * b2f(s10[r]) + w11 * b2f(s11[r]);
                float val = acc[im][jn][r] + rr * inv8[im][r] + sh8[im][r] + sp;
                size_t oi = ((size_t)b * 256 + c) * 4096 + l;
                if constexpr (F32) ((float*)P.outp)[oi] = val;
                else               ((u16*)P.outp)[oi]  = f2b(val);
            }
        }
    }
}

// ---------------------------------------------------------------------------
// Mega kernel: all phases, grid-wide sync between them. 512 blocks x 512 thr,
// 2 blocks/CU co-resident (launch_bounds caps VGPR at 128; LDS ~33 KB).
// ---------------------------------------------------------------------------
__global__ __launch_bounds__(512, 4) void k_mega(KP P)
{
    namespace cg = cooperative_groups;
    cg::grid_group grid = cg::this_grid();
    __shared__ u16 sh_t[64][66];
    __shared__ float sh_red[2][8];
    __shared__ float sh_xred[2][4][64][12];
    __shared__ int sh_ok;

    const int blk = blockIdx.x, tid = threadIdx.x;
    const bool f32 = detect_f32((const u16*)P.resnet);

    ph_prep(P, blk, tid, f32, sh_t, &sh_ok);
    grid.sync();
    ph_scpmm(P, blk, tid);
    grid.sync();
    ph_ln(P, blk, tid, sh_red);
    grid.sync();
    ph_gemm_in(P, blk, tid);
    grid.sync();
    ph_xproj(P, blk, tid, sh_xred);
    grid.sync();
    ph_scan1(P, blk, tid);
    grid.sync();
    ph_scan2(P, blk, tid);
    grid.sync();
    ph_scan3(P, blk, tid);
    grid.sync();
    if (f32) ph_out<true>(P, blk, tid);
    else     ph_out<false>(P, blk, tid);
}

// --- fallback wrappers (plain launches) in case cooperative launch fails ---
__global__ __launch_bounds__(512, 4) void k_p0(KP P) {
    __shared__ u16 sh_t[64][66]; __shared__ int sh_ok;
    ph_prep(P, blockIdx.x, threadIdx.x, detect_f32((const u16*)P.resnet), sh_t, &sh_ok);
}
__global__ __launch_bounds__(512, 4) void k_p1(KP P) { ph_scpmm(P, blockIdx.x, threadIdx.x); }
__global__ __launch_bounds__(512, 4) void k_p2(KP P) {
    __shared__ float sh_red[2][8];
    ph_ln(P, blockIdx.x, threadIdx.x, sh_red);
}
__global__ __launch_bounds__(512, 4) void k_p3(KP P) { ph_gemm_in(P, blockIdx.x, threadIdx.x); }
__global__ __launch_bounds__(512, 4) void k_p4(KP P) {
    __shared__ float sh_xred[2][4][64][12];
    ph_xproj(P, blockIdx.x, threadIdx.x, sh_xred);
}
__global__ __launch_bounds__(512, 4) void k_p5(KP P) { ph_scan1(P, blockIdx.x, threadIdx.x); }
__global__ __launch_bounds__(512, 4) void k_p6(KP P) { ph_scan2(P, blockIdx.x, threadIdx.x); }
__global__ __launch_bounds__(512, 4) void k_p7(KP P) { ph_scan3(P, blockIdx.x, threadIdx.x); }
__global__ __launch_bounds__(512, 4) void k_p8(KP P) {
    if (detect_f32((const u16*)P.resnet)) ph_out<true>(P, blockIdx.x, threadIdx.x);
    else                                  ph_out<false>(P, blockIdx.x, threadIdx.x);
}

// ---------------------------------------------------------------------------
extern "C" void kernel_launch(void* const* d_in, const int* in_sizes, int n_in,
                              void* d_out, int out_size, void* d_ws, size_t ws_size,
                              hipStream_t stream)
{
    KP P;
    P.resnet = d_in[0];
    P.scp    = d_in[1];
    P.spw    = d_in[2];
    P.sg     = d_in[3];
    P.sb     = d_in[4];
    P.sm     = d_in[5];
    P.sv     = d_in[6];
    P.rg     = d_in[7];
    P.rb     = d_in[8];
    P.rm     = d_in[9];
    P.rv     = d_in[10];
    P.lg     = d_in[11];
    P.lb     = d_in[12];
    P.inw    = d_in[13];
    P.cw     = d_in[14];
    P.cb     = d_in[15];
    P.xpw    = d_in[16];
    P.dtw    = d_in[17];
    P.dtb    = d_in[18];
    P.alog   = d_in[19];
    P.Dw     = d_in[20];
    P.opw    = d_in[21];

    // Workspace layout (~69 MB of the 256 MiB ws)
    char* ws  = (char*)d_ws;
    P.w16     = (u16*)(ws + 4096);         // 1.09 MB arena (+flag)
    P.sp16    = (u16*)(ws + 2097152);      // 1 MB
    P.scpT    = (u16*)(ws + 4194304);      // 2 MB
    P.resnetT = (u16*)(ws + 8388608);      // 4 MB
    P.xn      = (u16*)(ws + 12582912);     // 4 MB
    P.xz      = (u16*)(ws + 16777216);     // 16 MB [b][l][1024] (xm | z)
    P.xdf     = (float*)(ws + 33554432);   // 1.5 MB f32 [b][l][48]
    P.y       = (u16*)(ws + 35651584);     // 8 MB
    const size_t tail0 = 44040192;
    P.cAH     = (unsigned*)(ws + tail0);                    // 16 MB packed (ap|h)
    P.hIn     = (u16*)(ws + tail0 + (size_t)NCK * 65536);   // 8 MB
    P.outp    = d_out;

    void* args[] = { (void*)&P };
    hipError_t err = hipLaunchCooperativeKernel(
        (const void*)k_mega, dim3(512), dim3(512), args, 0, stream);
    if (err != hipSuccess) {
        (void)hipGetLastError();   // clear error state; fall back to 9 launches
        k_p0<<<dim3(512), dim3(512), 0, stream>>>(P);
        k_p1<<<dim3(512), dim3(512), 0, stream>>>(P);
        k_p2<<<dim3(512), dim3(512), 0, stream>>>(P);
        k_p3<<<dim3(512), dim3(512), 0, stream>>>(P);
        k_p4<<<dim3(512), dim3(512), 0, stream>>>(P);
        k_p5<<<dim3(512), dim3(512), 0, stream>>>(P);
        k_p6<<<dim3(512), dim3(512), 0, stream>>>(P);
        k_p7<<<dim3(512), dim3(512), 0, stream>>>(P);
        k_p8<<<dim3(512), dim3(512), 0, stream>>>(P);
    }
}

// Round 7
// 240.853 us; speedup vs baseline: 3.1187x; 3.1187x over previous
//
#include <hip/hip_runtime.h>
#include <hip/hip_bf16.h>
#include <math.h>

typedef unsigned short u16;
typedef __attribute__((ext_vector_type(8))) short short8;
typedef __attribute__((ext_vector_type(4))) float f32x4;
typedef __attribute__((ext_vector_type(4))) unsigned short u16x4;

#define DEVINL static __device__ __forceinline__

DEVINL float b2f(u16 x) {
    union { unsigned u; float f; } v; v.u = ((unsigned)x) << 16; return v.f;
}
DEVINL u16 f2b(float f) {
    union { unsigned u; float f; } v; v.f = f;
    unsigned u = v.u;
    return (u16)((u + 0x7fffu + ((u >> 16) & 1u)) >> 16);
}
DEVINL float silu(float x) { return x * __fdividef(1.f, 1.f + __expf(-x)); }
DEVINL float ld_any(bool f32, const void* p, size_t i) {
    return f32 ? ((const float*)p)[i] : b2f(((const u16*)p)[i]);
}
template<bool F32> DEVINL float LDs(const void* p, size_t i) {
    if constexpr (F32) return ((const float*)p)[i];
    else               return b2f(((const u16*)p)[i]);
}

// Inline dtype detect: sample the 64 EVEN u16s of resnet. f32 input -> even
// u16s are mantissa halves (~46% trigger each); bf16 -> 0 trigger.
DEVINL bool detect_f32(const u16* __restrict__ raw) {
    int cnt = 0;
#pragma unroll
    for (int i = 0; i < 64; ++i) {
        float v = b2f(raw[i * 2]);
        if (!(fabsf(v) <= 1e3f)) cnt++;
    }
    return cnt > 0;
}

// --- converted-weights arena: element offsets inside w16 (bf16) ---
#define O_INW  0        /* 1024*256 */
#define O_XPW  262144   /* 48*512 */
#define O_OPW  286720   /* 256*512 */
#define O_SPW  417792   /* 256*512 */
#define O_CW   548864   /* 512*3 */
#define O_CB   550400   /* 512 */
#define O_DTW  550912   /* 512*16 */
#define O_ALOG 559104   /* 512*16 */
#define O_DTB  567296   /* 512 */
#define O_DW   567808   /* 512 */
#define O_SG   568320
#define O_SB   568576
#define O_SM   568832
#define O_SV   569088
#define O_RG   569344
#define O_RB   569600
#define O_RM   569856
#define O_RV   570112
#define O_LG   570368
#define O_LB   570624
#define N_CVT  570880
#define O_FLAG 570880   /* A_log == log(arange(1..16)) structure flag */

// NOTE (r6->r7): cooperative-launch mega kernel abandoned — r5/r6 both died
// in the harness (Trio nursery, no pytest output) with it; r1's 9-launch
// pipeline (250us, passed) restored. Single change vs r1: k_xproj gets a
// 4-way K-split (512 blocks x 256 thr, 8 waves/CU vs r1's 2 waves/CU).

// ---------------------------------------------------------------------------
// k_prep: weight/param cvt (blocks 0..2229) + scp transpose (2230..2485)
// + resnet transpose (2486..2997) + A_log structure check (2998).
// ---------------------------------------------------------------------------
DEVINL void tr_tile(bool f32, const void* src, u16* dst, int R, int C,
                    int c0, int r0, int b, int tid)
{
    __shared__ u16 t[64][66];
    int lane = tid & 63, grp = tid >> 6;
#pragma unroll
    for (int j = 0; j < 16; ++j) {
        int rl = j * 4 + grp;
        t[rl][lane] = f2b(ld_any(f32, src, ((size_t)b * R + r0 + rl) * C + c0 + lane));
    }
    __syncthreads();
#pragma unroll
    for (int j = 0; j < 16; ++j) {
        int cl = j * 4 + grp;
        dst[((size_t)b * C + c0 + cl) * R + r0 + lane] = t[lane][cl];
    }
}

__global__ __launch_bounds__(256) void k_prep(
    const void* inw, const void* xpw, const void* opw, const void* spw,
    const void* cw, const void* cb, const void* dtw, const void* alog,
    const void* dtb, const void* Dw,
    const void* sg, const void* sb, const void* sm, const void* sv,
    const void* rg, const void* rb, const void* rm, const void* rv,
    const void* lg, const void* lb,
    const void* scp, const void* resnet,
    u16* __restrict__ w16, u16* __restrict__ scpT, u16* __restrict__ resnetT)
{
    bool f32 = detect_f32((const u16*)resnet);
    int bid = blockIdx.x, tid = threadIdx.x;
    if (bid < 2230) {
        int i = bid * 256 + tid;             // i < 570880 = N_CVT exactly
        const void* src; int off = i;
        if      (i < O_XPW)  { src = inw; }
        else if (i < O_OPW)  { src = xpw;  off = i - O_XPW; }
        else if (i < O_SPW)  { src = opw;  off = i - O_OPW; }
        else if (i < O_CW)   { src = spw;  off = i - O_SPW; }
        else if (i < O_CB)   { src = cw;   off = i - O_CW; }
        else if (i < O_DTW)  { src = cb;   off = i - O_CB; }
        else if (i < O_ALOG) { src = dtw;  off = i - O_DTW; }
        else if (i < O_DTB)  { src = alog; off = i - O_ALOG; }
        else if (i < O_DW)   { src = dtb;  off = i - O_DTB; }
        else if (i < O_SG)   { src = Dw;   off = i - O_DW; }
        else if (i < O_SB)   { src = sg;   off = i - O_SG; }
        else if (i < O_SM)   { src = sb;   off = i - O_SB; }
        else if (i < O_SV)   { src = sm;   off = i - O_SM; }
        else if (i < O_RG)   { src = sv;   off = i - O_SV; }
        else if (i < O_RB)   { src = rg;   off = i - O_RG; }
        else if (i < O_RM)   { src = rb;   off = i - O_RB; }
        else if (i < O_RV)   { src = rm;   off = i - O_RM; }
        else if (i < O_LG)   { src = rv;   off = i - O_RV; }
        else if (i < O_LB)   { src = lg;   off = i - O_LG; }
        else                 { src = lb;   off = i - O_LB; }
        w16[i] = f2b(ld_any(f32, src, off));
    } else if (bid < 2230 + 256) {
        int t = bid - 2230;                  // scp: R=512, C=1024
        tr_tile(f32, scp, scpT, 512, 1024, (t & 15) * 64, ((t >> 4) & 7) * 64, t >> 7, tid);
    } else if (bid < 2998) {
        int t = bid - 2486;                  // resnet: R=256, C=4096
        tr_tile(f32, resnet, resnetT, 256, 4096, (t & 63) * 64, ((t >> 6) & 3) * 64, t >> 8, tid);
    } else {
        // A_log structure check: a[d][s] == -(s+1) (rel tol 3% covers bf16 rounding)
        __shared__ int oksh;
        if (tid == 0) oksh = 1;
        __syncthreads();
        bool ok = true;
        for (int i = tid; i < 512 * 16; i += 256) {
            int s = i & 15;
            float av = -__expf(ld_any(f32, alog, i));
            if (fabsf(av + (float)(s + 1)) > 0.03f * (float)(s + 1)) ok = false;
        }
        if (!ok) atomicAnd(&oksh, 0);
        __syncthreads();
        if (tid == 0) w16[O_FLAG] = (u16)oksh;
    }
}

// ---------------------------------------------------------------------------
// k_scpmm: sp16[p][o] = BN(sum_c scpT[p][c] * spw[o][c]). MFMA, all bf16.
// M=2048, N=256, K=512. grid (32, 4), block 256 (4 waves 2x2).
// ---------------------------------------------------------------------------
__global__ __launch_bounds__(256) void k_scpmm(
    const u16* __restrict__ scpT, const u16* __restrict__ w16,
    u16* __restrict__ sp16)
{
    const int N = 256, K = 512;
    int tid = threadIdx.x, lane = tid & 63, wid = tid >> 6;
    int ln = lane & 15, q = lane >> 4;
    int m0 = blockIdx.x * 64 + (wid & 1) * 32;
    int n0 = blockIdx.y * 64 + (wid >> 1) * 32;
    f32x4 acc00 = {0.f,0.f,0.f,0.f}, acc01 = acc00, acc10 = acc00, acc11 = acc00;
    const u16* Ap0 = scpT + (size_t)(m0 + ln) * K + q * 8;
    const u16* Ap1 = Ap0 + (size_t)16 * K;
    const u16* Wp = w16 + O_SPW;
#pragma unroll 4
    for (int k0 = 0; k0 < K; k0 += 32) {
        int kk = k0 + q * 8;
        short8 a0 = *reinterpret_cast<const short8*>(Ap0 + k0);
        short8 a1 = *reinterpret_cast<const short8*>(Ap1 + k0);
        short8 b0 = *reinterpret_cast<const short8*>(Wp + (size_t)(n0 + ln) * K + kk);
        short8 b1 = *reinterpret_cast<const short8*>(Wp + (size_t)(n0 + ln + 16) * K + kk);
        acc00 = __builtin_amdgcn_mfma_f32_16x16x32_bf16(a0, b0, acc00, 0, 0, 0);
        acc01 = __builtin_amdgcn_mfma_f32_16x16x32_bf16(a0, b1, acc01, 0, 0, 0);
        acc10 = __builtin_amdgcn_mfma_f32_16x16x32_bf16(a1, b0, acc10, 0, 0, 0);
        acc11 = __builtin_amdgcn_mfma_f32_16x16x32_bf16(a1, b1, acc11, 0, 0, 0);
    }
    int r0 = m0 + q * 4, c0 = n0 + ln;
    float inv0 = b2f(w16[O_SG + c0]) * rsqrtf(b2f(w16[O_SV + c0]) + 1e-5f);
    float sh0  = b2f(w16[O_SB + c0]) - b2f(w16[O_SM + c0]) * inv0;
    float inv1 = b2f(w16[O_SG + c0 + 16]) * rsqrtf(b2f(w16[O_SV + c0 + 16]) + 1e-5f);
    float sh1  = b2f(w16[O_SB + c0 + 16]) - b2f(w16[O_SM + c0 + 16]) * inv1;
#pragma unroll
    for (int r = 0; r < 4; ++r) {
        sp16[(size_t)(r0 + r) * N + c0]           = f2b(acc00[r] * inv0 + sh0);
        sp16[(size_t)(r0 + r) * N + c0 + 16]      = f2b(acc01[r] * inv1 + sh1);
        sp16[(size_t)(r0 + 16 + r) * N + c0]      = f2b(acc10[r] * inv0 + sh0);
        sp16[(size_t)(r0 + 16 + r) * N + c0 + 16] = f2b(acc11[r] * inv1 + sh1);
    }
}

// ---------------------------------------------------------------------------
// k_ln: res-BN + bilinear + add -> LayerNorm -> xn. 8 rows per block.
// grid (512, B), block 256 (thread = channel).
// ---------------------------------------------------------------------------
__global__ __launch_bounds__(256) void k_ln(
    const u16* __restrict__ resnetT, const u16* __restrict__ w16,
    const u16* __restrict__ sp16, u16* __restrict__ xn)
{
    __shared__ float red[8];
    int c = threadIdx.x, b = blockIdx.y;
    float inv = b2f(w16[O_RG + c]) * rsqrtf(b2f(w16[O_RV + c]) + 1e-5f);
    float sh  = b2f(w16[O_RB + c]) - b2f(w16[O_RM + c]) * inv;
    float lgv = b2f(w16[O_LG + c]), lbv = b2f(w16[O_LB + c]);
    const u16* spc = sp16 + (size_t)b * 1024 * 256 + c;
    for (int j = 0; j < 8; ++j) {
        int l = blockIdx.x * 8 + j;
        int h = l >> 6, w = l & 63;
        float rr = b2f(resnetT[((size_t)b * 4096 + l) * 256 + c]);
        float rn = rr * inv + sh;
        float xh = 0.5f * h - 0.25f; int jh = (int)floorf(xh); float fh = xh - jh;
        float xw = 0.5f * w - 0.25f; int jw = (int)floorf(xw); float fw = xw - jw;
        int h0 = jh < 0 ? 0 : jh, h1 = jh + 1 > 31 ? 31 : jh + 1;
        int w0 = jw < 0 ? 0 : jw, w1 = jw + 1 > 31 ? 31 : jw + 1;
        float v00 = b2f(spc[(size_t)(h0 * 32 + w0) * 256]), v01 = b2f(spc[(size_t)(h0 * 32 + w1) * 256]);
        float v10 = b2f(spc[(size_t)(h1 * 32 + w0) * 256]), v11 = b2f(spc[(size_t)(h1 * 32 + w1) * 256]);
        float sp = (1.f - fh) * ((1.f - fw) * v00 + fw * v01)
                 + fh * ((1.f - fw) * v10 + fw * v11);
        float fv = rn + sp;

        float s = fv, s2 = fv * fv;
#pragma unroll
        for (int off = 1; off < 64; off <<= 1) {
            s  += __shfl_xor(s, off);
            s2 += __shfl_xor(s2, off);
        }
        int wv = c >> 6;
        if ((c & 63) == 0) { red[wv] = s; red[4 + wv] = s2; }
        __syncthreads();
        float S  = red[0] + red[1] + red[2] + red[3];
        float S2 = red[4] + red[5] + red[6] + red[7];
        __syncthreads();
        float mu   = S * (1.f / 256.f);
        float var  = S2 * (1.f / 256.f) - mu * mu;
        float rstd = rsqrtf(var + 1e-5f);
        xn[((size_t)b * 4096 + l) * 256 + c] = f2b((fv - mu) * rstd * lgv + lbv);
    }
}

// ---------------------------------------------------------------------------
// in_proj GEMM, both halves: xz[row][n], n in [0,1024). M=8192, K=256.
// Block tile 128m x 128n (4 waves 2x2), wave tile 64x64 (16 MFMA/k-iter).
// grid (64, 8), block 256.
// ---------------------------------------------------------------------------
__global__ __launch_bounds__(256) void k_gemm_in(
    const u16* __restrict__ A, const u16* __restrict__ w16, u16* __restrict__ Out)
{
    const int N = 1024, K = 256;
    int tid = threadIdx.x, lane = tid & 63, wid = tid >> 6;
    int ln = lane & 15, q = lane >> 4;
    int m0 = blockIdx.x * 128 + (wid & 1) * 64;
    int n0 = blockIdx.y * 128 + (wid >> 1) * 64;
    f32x4 acc[4][4];
#pragma unroll
    for (int i = 0; i < 4; ++i)
#pragma unroll
        for (int j = 0; j < 4; ++j) acc[i][j] = {0.f,0.f,0.f,0.f};
    const u16* Ap = A + (size_t)(m0 + ln) * K + q * 8;
    const u16* Bp = w16 + O_INW + (size_t)(n0 + ln) * K + q * 8;
#pragma unroll
    for (int k0 = 0; k0 < K; k0 += 32) {
        short8 a[4], bb[4];
#pragma unroll
        for (int i = 0; i < 4; ++i)
            a[i] = *reinterpret_cast<const short8*>(Ap + (size_t)(16 * i) * K + k0);
#pragma unroll
        for (int j = 0; j < 4; ++j)
            bb[j] = *reinterpret_cast<const short8*>(Bp + (size_t)(16 * j) * K + k0);
#pragma unroll
        for (int i = 0; i < 4; ++i)
#pragma unroll
            for (int j = 0; j < 4; ++j)
                acc[i][j] = __builtin_amdgcn_mfma_f32_16x16x32_bf16(a[i], bb[j], acc[i][j], 0, 0, 0);
    }
    int r0 = m0 + q * 4, c0 = n0 + ln;
#pragma unroll
    for (int i = 0; i < 4; ++i)
#pragma unroll
        for (int j = 0; j < 4; ++j)
#pragma unroll
            for (int r = 0; r < 4; ++r)
                Out[(size_t)(r0 + 16 * i + r) * N + c0 + 16 * j] = f2b(acc[i][j][r]);
}

// ---------------------------------------------------------------------------
// on-the-fly u fragment: u[row][kk0..kk0+8) = silu(causal conv3 of xm half of xz)
// ---------------------------------------------------------------------------
DEVINL short8 u_frag(const u16* __restrict__ xz, const u16* __restrict__ w16,
                     int row, int kk0)
{
    int l = row & 4095;
    const u16* p = xz + (size_t)row * 1024 + kk0;
    short8 zz = {0,0,0,0,0,0,0,0};
    short8 x0 = *reinterpret_cast<const short8*>(p);
    short8 x1 = (l >= 1) ? *reinterpret_cast<const short8*>(p - 1024) : zz;
    short8 x2 = (l >= 2) ? *reinterpret_cast<const short8*>(p - 2048) : zz;
    short8 r;
#pragma unroll
    for (int j = 0; j < 8; ++j) {
        int d = kk0 + j;
        float acc = b2f(w16[O_CB + d])
                  + b2f((u16)x2[j]) * b2f(w16[O_CW + d * 3])
                  + b2f((u16)x1[j]) * b2f(w16[O_CW + d * 3 + 1])
                  + b2f((u16)x0[j]) * b2f(w16[O_CW + d * 3 + 2]);
        r[j] = (short)f2b(silu(acc));
    }
    return r;
}

// ---------------------------------------------------------------------------
// x_proj GEMM, conv-on-the-fly A: xdf[row][n] f32, N=48, K=512.
// r7: 4-way K-split. grid (512), block 256: 4 waves each take K=128 of the
// same 16-row tile; partials summed via LDS. 8 waves/CU (r1: 2 waves/CU).
// ---------------------------------------------------------------------------
__global__ __launch_bounds__(256) void k_xproj(
    const u16* __restrict__ xz, const u16* __restrict__ w16, float* __restrict__ xdf)
{
    __shared__ float xred[4][64][12];
    int tid = threadIdx.x, lane = tid & 63, wid = tid >> 6;  // wid = K-split
    int ln = lane & 15, q = lane >> 4;
    int m0 = blockIdx.x * 16;
    const u16* Wp = w16 + O_XPW;
    f32x4 acc[3];
#pragma unroll
    for (int j = 0; j < 3; ++j) acc[j] = {0.f,0.f,0.f,0.f};
    int kb = wid * 128;
    for (int k0 = kb; k0 < kb + 128; k0 += 32) {
        int kk0 = k0 + q * 8;
        short8 a0 = u_frag(xz, w16, m0 + ln, kk0);
#pragma unroll
        for (int j = 0; j < 3; ++j) {
            short8 bj = *reinterpret_cast<const short8*>(Wp + (size_t)(16 * j + ln) * 512 + kk0);
            acc[j] = __builtin_amdgcn_mfma_f32_16x16x32_bf16(a0, bj, acc[j], 0, 0, 0);
        }
    }
#pragma unroll
    for (int j = 0; j < 3; ++j)
#pragma unroll
        for (int r = 0; r < 4; ++r) xred[wid][lane][j * 4 + r] = acc[j][r];
    __syncthreads();
    if (wid == 0) {
#pragma unroll
        for (int j = 0; j < 3; ++j)
#pragma unroll
            for (int r = 0; r < 4; ++r) {
                float v = xred[0][lane][j * 4 + r] + xred[1][lane][j * 4 + r]
                        + xred[2][lane][j * 4 + r] + xred[3][lane][j * 4 + r];
                xdf[(size_t)(m0 + q * 4 + r) * 48 + 16 * j + ln] = v;
            }
    }
}

// per-step shared scan prelude: conv -> silu -> dt-dot -> softplus
#define SCAN_PRELUDE()                                                        \
    const float* xr = xr0 + (size_t)il * 48;                                  \
    float x0 = b2f(xz[xbase + (size_t)il * 1024]);                            \
    float uv = silu(cbv + cw0 * x2 + cw1 * x1 + cw2 * x0);                    \
    float pa = 0.f, pb = 0.f, pc = 0.f, pq = 0.f;                             \
    _Pragma("unroll")                                                         \
    for (int j = 0; j < 4; ++j) {                                             \
        pa += xr[j]      * wdt[j];      pb += xr[4 + j]  * wdt[4 + j];        \
        pc += xr[8 + j]  * wdt[8 + j];  pq += xr[12 + j] * wdt[12 + j];       \
    }                                                                         \
    float accd = bias + ((pa + pb) + (pc + pq));                              \
    float dtv = accd > 15.f ? accd : __logf(1.f + __expf(accd));              \
    float du = dtv * uv;

// ---------------------------------------------------------------------------
// scan1: per-chunk local scan; stores packed (ap, h_local) per state.
// grid (NC, B), block 512 (thread = d).
// ---------------------------------------------------------------------------
__global__ __launch_bounds__(512) void k_scan1(
    const u16* __restrict__ xz, const float* __restrict__ xdf,
    const u16* __restrict__ w16, unsigned* __restrict__ cAH,
    int NC, int CL)
{
    int d = threadIdx.x, ck = blockIdx.x, b = blockIdx.y;
    float wdt[16];
#pragma unroll
    for (int j = 0; j < 16; ++j) wdt[j] = b2f(w16[O_DTW + d * 16 + j]);
    float bias = b2f(w16[O_DTB + d]);
    float cw0 = b2f(w16[O_CW + d * 3]), cw1 = b2f(w16[O_CW + d * 3 + 1]),
          cw2 = b2f(w16[O_CW + d * 3 + 2]), cbv = b2f(w16[O_CB + d]);
    int l0 = ck * CL;
    size_t xbase = ((size_t)b * 4096 + l0) * 1024 + d;
    float x2 = (l0 >= 2) ? b2f(xz[xbase - 2048]) : 0.f;
    float x1 = (l0 >= 1) ? b2f(xz[xbase - 1024]) : 0.f;
    const float* xr0 = xdf + ((size_t)b * 4096 + l0) * 48;
    size_t obase = (((size_t)b * NC + ck) * 16) * 512 + d;
    float h[16];
#pragma unroll
    for (int s = 0; s < 16; ++s) h[s] = 0.f;

    if (w16[O_FLAG]) {
        float sdt = 0.f;
#pragma unroll 2
        for (int il = 0; il < CL; ++il) {
            SCAN_PRELUDE();
            sdt += dtv;
            float e1 = __expf(-dtv);
            float e2 = e1 * e1, e3 = e2 * e1, e4 = e2 * e2;
            float e8 = e4 * e4, e12 = e8 * e4;
            float inn[4] = {e1, e2, e3, e4};
            float bas[4] = {1.f, e4, e8, e12};
#pragma unroll
            for (int s = 0; s < 16; ++s)
                h[s] = (bas[s >> 2] * inn[s & 3]) * h[s] + du * xr[16 + s];
            x2 = x1; x1 = x0;
        }
        float E1 = __expf(-sdt);
        float E2 = E1 * E1, E3 = E2 * E1, E4 = E2 * E2;
        float E8 = E4 * E4, E12 = E8 * E4;
        float iN[4] = {E1, E2, E3, E4};
        float bA[4] = {1.f, E4, E8, E12};
#pragma unroll
        for (int s = 0; s < 16; ++s)
            cAH[obase + (size_t)s * 512] =
                (unsigned)f2b(bA[s >> 2] * iN[s & 3]) | ((unsigned)f2b(h[s]) << 16);
    } else {
        float a[16], ap[16];
#pragma unroll
        for (int s = 0; s < 16; ++s) {
            a[s] = -__expf(b2f(w16[O_ALOG + d * 16 + s]));
            ap[s] = 1.f;
        }
        for (int il = 0; il < CL; ++il) {
            SCAN_PRELUDE();
#pragma unroll
            for (int s = 0; s < 16; ++s) {
                float dA = __expf(dtv * a[s]);
                h[s] = dA * h[s] + du * xr[16 + s];
                ap[s] *= dA;
            }
            x2 = x1; x1 = x0;
        }
#pragma unroll
        for (int s = 0; s < 16; ++s)
            cAH[obase + (size_t)s * 512] =
                (unsigned)f2b(ap[s]) | ((unsigned)f2b(h[s]) << 16);
    }
}

// ---------------------------------------------------------------------------
// scan2: cross-chunk recurrence; hIn[ck] := h_in(ck). grid (16, 4, B), blk 128.
// Packed u32 load (ap|h); unroll 8 prefetches ahead (hIn disjoint from cAH).
// ---------------------------------------------------------------------------
__global__ __launch_bounds__(128) void k_scan2(
    const unsigned* __restrict__ cAH, u16* __restrict__ hIn, int NC)
{
    int d = blockIdx.y * 128 + threadIdx.x, s = blockIdx.x, b = blockIdx.z;
    float h = 0.f;
#pragma unroll 8
    for (int ck = 0; ck < NC; ++ck) {
        size_t idx = (((size_t)b * NC + ck) * 16 + s) * 512 + d;
        unsigned v = cAH[idx];
        float aP = b2f((u16)(v & 0xffffu));
        float hE = b2f((u16)(v >> 16));
        hIn[idx] = f2b(h);
        h = aP * h + hE;
    }
}

// ---------------------------------------------------------------------------
// scan3: replay from h_in; y = (h.C + u*D) * silu(z). grid (NC, B), block 512.
// ---------------------------------------------------------------------------
__global__ __launch_bounds__(512) void k_scan3(
    const u16* __restrict__ xz, const float* __restrict__ xdf,
    const u16* __restrict__ w16, const u16* __restrict__ hIn,
    u16* __restrict__ y, int NC, int CL)
{
    int d = threadIdx.x, ck = blockIdx.x, b = blockIdx.y;
    float wdt[16];
#pragma unroll
    for (int j = 0; j < 16; ++j) wdt[j] = b2f(w16[O_DTW + d * 16 + j]);
    float bias = b2f(w16[O_DTB + d]);
    float Dv = b2f(w16[O_DW + d]);
    float cw0 = b2f(w16[O_CW + d * 3]), cw1 = b2f(w16[O_CW + d * 3 + 1]),
          cw2 = b2f(w16[O_CW + d * 3 + 2]), cbv = b2f(w16[O_CB + d]);
    int l0 = ck * CL;
    size_t xbase = ((size_t)b * 4096 + l0) * 1024 + d;
    float x2 = (l0 >= 2) ? b2f(xz[xbase - 2048]) : 0.f;
    float x1 = (l0 >= 1) ? b2f(xz[xbase - 1024]) : 0.f;
    const float* xr0 = xdf + ((size_t)b * 4096 + l0) * 48;
    size_t obase = (((size_t)b * NC + ck) * 16) * 512 + d;
    float h[16];
#pragma unroll
    for (int s = 0; s < 16; ++s) h[s] = b2f(hIn[obase + (size_t)s * 512]);

    if (w16[O_FLAG]) {
#pragma unroll 2
        for (int il = 0; il < CL; ++il) {
            SCAN_PRELUDE();
            float e1 = __expf(-dtv);
            float e2 = e1 * e1, e3 = e2 * e1, e4 = e2 * e2;
            float e8 = e4 * e4, e12 = e8 * e4;
            float inn[4] = {e1, e2, e3, e4};
            float bas[4] = {1.f, e4, e8, e12};
            float yv = 0.f;
#pragma unroll
            for (int s = 0; s < 16; ++s) {
                h[s] = (bas[s >> 2] * inn[s & 3]) * h[s] + du * xr[16 + s];
                yv += h[s] * xr[32 + s];
            }
            size_t row = (size_t)b * 4096 + l0 + il;
            yv += uv * Dv;
            float zv = b2f(xz[row * 1024 + 512 + d]);
            yv *= silu(zv);
            y[row * 512 + d] = f2b(yv);
            x2 = x1; x1 = x0;
        }
    } else {
        float a[16];
#pragma unroll
        for (int s = 0; s < 16; ++s)
            a[s] = -__expf(b2f(w16[O_ALOG + d * 16 + s]));
        for (int il = 0; il < CL; ++il) {
            SCAN_PRELUDE();
            float yv = 0.f;
#pragma unroll
            for (int s = 0; s < 16; ++s) {
                float dA = __expf(dtv * a[s]);
                h[s] = dA * h[s] + du * xr[16 + s];
                yv += h[s] * xr[32 + s];
            }
            size_t row = (size_t)b * 4096 + l0 + il;
            yv += uv * Dv;
            float zv = b2f(xz[row * 1024 + 512 + d]);
            yv *= silu(zv);
            y[row * 512 + d] = f2b(yv);
            x2 = x1; x1 = x0;
        }
    }
}

// ---------------------------------------------------------------------------
// out_proj GEMM (m = channel, n = sequence) + fused-recompute epilogue.
// Block tile 64chan x 128seq (4 waves 2x2), wave 32x64. grid (4, 64), block 256.
// (256 blocks = 1/CU; halving the grid hurt in a prior session. Keep.)
// ---------------------------------------------------------------------------
template<bool F32> DEVINL void out_body(
    const u16* Y, const u16* w16, const void* resnet,
    const u16* sp16, void* outp)
{
    const int K = 512;
    int tid = threadIdx.x, lane = tid & 63, wid = tid >> 6;
    int ln = lane & 15, q = lane >> 4;
    int m0 = blockIdx.x * 64 + (wid & 1) * 32;    // channel dim (256)
    int n0 = blockIdx.y * 128 + (wid >> 1) * 64;  // sequence dim (8192)
    f32x4 acc[2][4];
#pragma unroll
    for (int i = 0; i < 2; ++i)
#pragma unroll
        for (int j = 0; j < 4; ++j) acc[i][j] = {0.f,0.f,0.f,0.f};
    const u16* Ap0 = w16 + O_OPW + (size_t)(m0 + ln) * K + q * 8;
    const u16* Ap1 = Ap0 + (size_t)16 * K;
    const u16* Bp  = Y + (size_t)(n0 + ln) * K + q * 8;
#pragma unroll 2
    for (int k0 = 0; k0 < K; k0 += 32) {
        short8 a0 = *reinterpret_cast<const short8*>(Ap0 + k0);
        short8 a1 = *reinterpret_cast<const short8*>(Ap1 + k0);
#pragma unroll
        for (int j = 0; j < 4; ++j) {
            short8 bj = *reinterpret_cast<const short8*>(Bp + (size_t)(16 * j) * K + k0);
            acc[0][j] = __builtin_amdgcn_mfma_f32_16x16x32_bf16(a0, bj, acc[0][j], 0, 0, 0);
            acc[1][j] = __builtin_amdgcn_mfma_f32_16x16x32_bf16(a1, bj, acc[1][j], 0, 0, 0);
        }
    }
    int r0 = m0 + q * 4;
    int nb = n0 + ln;
    float inv8[2][4], sh8[2][4];
#pragma unroll
    for (int im = 0; im < 2; ++im)
#pragma unroll
        for (int r = 0; r < 4; ++r) {
            int c = r0 + 16 * im + r;
            float inv = b2f(w16[O_RG + c]) * rsqrtf(b2f(w16[O_RV + c]) + 1e-5f);
            inv8[im][r] = inv;
            sh8[im][r]  = b2f(w16[O_RB + c]) - b2f(w16[O_RM + c]) * inv;
        }
#pragma unroll
    for (int jn = 0; jn < 4; ++jn) {
        int n = nb + 16 * jn;
        int b = n >> 12, l = n & 4095;
        int hh = l >> 6, w = l & 63;
        float xh = 0.5f * hh - 0.25f; int jh = (int)floorf(xh); float fh = xh - jh;
        float xw = 0.5f * w - 0.25f;  int jw = (int)floorf(xw); float fw = xw - jw;
        int h0 = jh < 0 ? 0 : jh, h1 = jh + 1 > 31 ? 31 : jh + 1;
        int w0 = jw < 0 ? 0 : jw, w1 = jw + 1 > 31 ? 31 : jw + 1;
        float w00 = (1.f - fh) * (1.f - fw), w01 = (1.f - fh) * fw;
        float w10 = fh * (1.f - fw),         w11 = fh * fw;
        const u16* spb = sp16 + (size_t)b * 1024 * 256;
#pragma unroll
        for (int im = 0; im < 2; ++im) {
            int cb = r0 + 16 * im;
            u16x4 s00 = *reinterpret_cast<const u16x4*>(spb + (size_t)(h0 * 32 + w0) * 256 + cb);
            u16x4 s01 = *reinterpret_cast<const u16x4*>(spb + (size_t)(h0 * 32 + w1) * 256 + cb);
            u16x4 s10 = *reinterpret_cast<const u16x4*>(spb + (size_t)(h1 * 32 + w0) * 256 + cb);
            u16x4 s11 = *reinterpret_cast<const u16x4*>(spb + (size_t)(h1 * 32 + w1) * 256 + cb);
#pragma unroll
            for (int r = 0; r < 4; ++r) {
                int c = cb + r;
                float rr = LDs<F32>(resnet, ((size_t)b * 256 + c) * 4096 + l);
                float sp = w00 * b2f(s00[r]) + w01 * b2f(s01[r])
                         + w10 * b2f(s10[r]) + w11 * b2f(s11[r]);
                float val = acc[im][jn][r] + rr * inv8[im][r] + sh8[im][r] + sp;
                size_t oi = ((size_t)b * 256 + c) * 4096 + l;
                if constexpr (F32) ((float*)outp)[oi] = val;
                else               ((u16*)outp)[oi]  = f2b(val);
            }
        }
    }
}
__global__ __launch_bounds__(256) void k_out(
    const u16* Y, const u16* w16, const void* resnet,
    const u16* sp16, void* outp)
{
    if (detect_f32((const u16*)resnet)) out_body<true>(Y, w16, resnet, sp16, outp);
    else                                out_body<false>(Y, w16, resnet, sp16, outp);
}

// ---------------------------------------------------------------------------
extern "C" void kernel_launch(void* const* d_in, const int* in_sizes, int n_in,
                              void* d_out, int out_size, void* d_ws, size_t ws_size,
                              hipStream_t stream)
{
    const void* resnet = d_in[0];
    const void* scp    = d_in[1];
    const void* spw    = d_in[2];
    const void* sg     = d_in[3];
    const void* sb     = d_in[4];
    const void* sm     = d_in[5];
    const void* sv     = d_in[6];
    const void* rg     = d_in[7];
    const void* rb     = d_in[8];
    const void* rm     = d_in[9];
    const void* rv     = d_in[10];
    const void* lg     = d_in[11];
    const void* lb     = d_in[12];
    const void* inw    = d_in[13];
    const void* cw     = d_in[14];
    const void* cb     = d_in[15];
    const void* xpw    = d_in[16];
    const void* dtw    = d_in[17];
    const void* dtb    = d_in[18];
    const void* alog   = d_in[19];
    const void* Dw     = d_in[20];
    const void* opw    = d_in[21];

    // Workspace layout (~69 MB of the 256 MiB ws)
    char*  ws      = (char*)d_ws;
    u16*   w16     = (u16*)(ws + 4096);         // 1.09 MB arena (+flag)
    u16*   sp16    = (u16*)(ws + 2097152);      // 1 MB
    u16*   scpT    = (u16*)(ws + 4194304);      // 2 MB
    u16*   resnetT = (u16*)(ws + 8388608);      // 4 MB
    u16*   xn      = (u16*)(ws + 12582912);     // 4 MB
    u16*   xz      = (u16*)(ws + 16777216);     // 16 MB [b][l][1024] (xm | z)
    float* xdf     = (float*)(ws + 33554432);   // 1.5 MB f32 [b][l][48]
    u16*   y       = (u16*)(ws + 35651584);     // 8 MB
    const size_t tail0 = 44040192;

    // cAH: u32 packed (ap | h_local) = NC*65536 B; hIn: u16 = NC*32768 B
    int NC = 16;
    for (int cand = 256; cand >= 16; cand >>= 1) {
        if (tail0 + (size_t)cand * 98304 <= ws_size) { NC = cand; break; }
    }
    int CL = 4096 / NC;
    unsigned* cAH = (unsigned*)(ws + tail0);
    u16*      hIn = (u16*)(ws + tail0 + (size_t)NC * 65536);

    k_prep<<<dim3(2999), 256, 0, stream>>>(
        inw, xpw, opw, spw, cw, cb, dtw, alog, dtb, Dw,
        sg, sb, sm, sv, rg, rb, rm, rv, lg, lb,
        scp, resnet, w16, scpT, resnetT);
    k_scpmm<<<dim3(32, 4), 256, 0, stream>>>(scpT, w16, sp16);
    k_ln<<<dim3(512, 2), 256, 0, stream>>>(resnetT, w16, sp16, xn);
    k_gemm_in<<<dim3(64, 8), 256, 0, stream>>>(xn, w16, xz);
    k_xproj<<<dim3(512), 256, 0, stream>>>(xz, w16, xdf);
    k_scan1<<<dim3(NC, 2), 512, 0, stream>>>(xz, xdf, w16, cAH, NC, CL);
    k_scan2<<<dim3(16, 4, 2), 128, 0, stream>>>(cAH, hIn, NC);
    k_scan3<<<dim3(NC, 2), 512, 0, stream>>>(xz, xdf, w16, hIn, y, NC, CL);
    k_out<<<dim3(4, 64), 256, 0, stream>>>(y, w16, resnet, sp16, d_out);
}